// Round 5
// baseline (1168.618 us; speedup 1.0000x reference)
//
#include <hip/hip_runtime.h>
#include <hip/hip_bf16.h>

#define B_    8192
#define D_    2048
#define H_    4096
#define C_    64
#define HALF_ 1024
#define KIN_  1088   // HALF_ + C_

typedef __attribute__((ext_vector_type(8))) short bf16x8;
typedef __attribute__((ext_vector_type(4))) float f32x4;
typedef __attribute__((ext_vector_type(16))) float f32x16;

__device__ __forceinline__ unsigned short f2bf(float f) {
  __hip_bfloat16 h = __float2bfloat16(f);
  return *reinterpret_cast<unsigned short*>(&h);
}

__device__ __forceinline__ void gload16(const void* g, void* s) {
  __builtin_amdgcn_global_load_lds((const __attribute__((address_space(1))) void*)g,
                                   (__attribute__((address_space(3))) void*)s,
                                   16, 0, 0);
}

// W [K,N] fp32 row-major  ->  Wt [N,K] bf16 row-major (transpose + convert)
__global__ void convT(const float* __restrict__ W, unsigned short* __restrict__ Wt,
                      int K, int N) {
  __shared__ float tile[32][33];
  int tx = threadIdx.x & 31, ty = threadIdx.x >> 5;   // 32x8 threads
  int n0 = blockIdx.x * 32, k0 = blockIdx.y * 32;
#pragma unroll
  for (int i = 0; i < 4; ++i)
    tile[ty + i * 8][tx] = W[(size_t)(k0 + ty + i * 8) * N + n0 + tx];
  __syncthreads();
#pragma unroll
  for (int i = 0; i < 4; ++i)
    Wt[(size_t)(n0 + ty + i * 8) * K + k0 + tx] = f2bf(tile[tx][ty + i * 8]);
}

// A0[b, c<1024] = xsrc[b, 2c+par], A0[b, 1024:1088] = condition[b, .]  (bf16)
// float2 read keeps the stride-2 gather fully coalesced (8B/lane).
__global__ void build_act(const float* __restrict__ xsrc, const float* __restrict__ cond,
                          int par, unsigned short* __restrict__ A0) {
  int row = blockIdx.y;
  int col = blockIdx.x * 256 + threadIdx.x;
  if (col >= KIN_) return;
  float v;
  if (col < HALF_) {
    float2 p = ((const float2*)xsrc)[(size_t)row * (D_ / 2) + col];
    v = par ? p.y : p.x;
  } else {
    v = cond[(size_t)row * C_ + (col - HALF_)];
  }
  A0[(size_t)row * KIN_ + col] = f2bf(v);
}

// ---------------------------------------------------------------------------
// 8-phase 256x256 GEMM, BK=64, 8 waves (2Mx4N), 2-buffer LDS (128 KiB),
// counted vmcnt(6) — schedule/staging/swizzle identical to R3/R4 (verified,
// 0 bank conflicts). MFMA shape: 32x32x16 bf16 (2495 TF pipe vs 2075 for
// 16x16x32; half the instruction count). Per wave: 4x2 32x32 acc frags.
//   A frag (m,kk4): row = wr*128+m*32+(l&31), k = kk4*16 + (l>>5)*8 + e
//   B frag (n,kk4): col = wc*64 +n*32+(l&31), same k
//   C/D (verified m74/m101): col = l&31, row = (r&3)+8*(r>>2)+4*(l>>5)
// Slab layout unchanged: slab kk = k32-group of 32; line p = rows 2p,2p+1;
// logical chunk = ((row&1)<<2)|(k32>>3); physical = logical ^ (p&7).
// MODE 0: C = bf16(relu(A*Bt^T+bias)) coalesced via per-wave LDS bounce.
// MODE 1: fused coupling epilogue (S,T interleaved cols; scatter+partials).
// ---------------------------------------------------------------------------
template <int MODE>
__global__ __launch_bounds__(512, 2)
void gemm8p(const unsigned short* __restrict__ A,
            const unsigned short* __restrict__ Bt,
            const float* __restrict__ bias,
            unsigned short* __restrict__ Cout,
            const float* __restrict__ xold, float* __restrict__ xnew,
            float* __restrict__ part, int par,
            int M, int N, int K) {
  __shared__ unsigned short lds[65536];   // 128 KiB
  char* ldsb = (char*)lds;
  const int tid = threadIdx.x;
  const int w = tid >> 6, lane = tid & 63;
  const int l31 = lane & 31, hi = lane >> 5;
  const int wr = w >> 2, wc = w & 3;          // 2x4 waves, wave tile 128x64

  // XCD-aware block swizzle (nwg % 8 == 0 for all our grids)
  const int nbx = N >> 8;
  const int nwg = (int)gridDim.x;
  const int cpx = nwg >> 3;
  const int bid = (int)blockIdx.x;
  const int swz = (bid & 7) * cpx + (bid >> 3);
  const int by = swz / nbx, bx = swz - by * nbx;
  const int m0 = by << 8, n0 = bx << 8;

  // read-side swizzled offsets (32x32 frags). p&7 == pline&7 for all frags.
  const int pline = l31 >> 1;
  const int cb = ((lane & 1) << 2) | hi;                 // chunk bits 2,0
  const int chunkE = (cb ^ (pline & 7)) * 16;            // kk4 even
  const int chunkO = ((cb | 2) ^ (pline & 7)) * 16;      // kk4 odd
  const int Abase = (wr * 64 + pline) * 128;
  const int Bbase = 32768 + (wc * 32 + pline) * 128;
  // aoffs[kk4] (add m*2048), boffs[kk4] (add n*2048)
  int aoffs[4], boffs[4];
#pragma unroll
  for (int kk = 0; kk < 4; ++kk) {
    int slab = (kk >> 1) * 16384;
    int ch = (kk & 1) ? chunkO : chunkE;
    aoffs[kk] = slab + Abase + ch;
    boffs[kk] = slab + Bbase + ch;
  }

  // stage-side: per-slot (s=0,1) pre-swizzled global source; linear LDS dest
  int rS[2], kcolS[2];
#pragma unroll
  for (int s = 0; s < 2; ++s) {
    int q = s * 512 + w * 64 + lane;        // physical 16B chunk within slab
    int p = q >> 3, cph = q & 7;
    int clg = cph ^ (p & 7);                // logical chunk
    rS[s] = 2 * p + (clg >> 2);
    kcolS[s] = (clg & 3) * 8;
  }
  const unsigned short* sA0 = A + (size_t)(m0 + rS[0]) * K + kcolS[0];
  const unsigned short* sA1 = A + (size_t)(m0 + rS[1]) * K + kcolS[1];
  const unsigned short* sB0 = Bt + (size_t)(n0 + rS[0]) * K + kcolS[0];
  const unsigned short* sB1 = Bt + (size_t)(n0 + rS[1]) * K + kcolS[1];
  const int dst0 = w * 1024 + lane * 16;    // byte offset within slab (slot 0)

#define STAGE_A(KK, TILE, BUF) do {                                          \
    gload16(sA0 + (TILE) * 64 + (KK) * 32,                                   \
            ldsb + (BUF) + (KK) * 16384 + dst0);                             \
    gload16(sA1 + (TILE) * 64 + (KK) * 32,                                   \
            ldsb + (BUF) + (KK) * 16384 + 8192 + dst0);                      \
  } while (0)
#define STAGE_B(KK, TILE, BUF) do {                                          \
    gload16(sB0 + (TILE) * 64 + (KK) * 32,                                   \
            ldsb + (BUF) + 32768 + (KK) * 16384 + dst0);                     \
    gload16(sB1 + (TILE) * 64 + (KK) * 32,                                   \
            ldsb + (BUF) + 32768 + (KK) * 16384 + 8192 + dst0);              \
  } while (0)

  f32x16 acc[4][2];
#pragma unroll
  for (int m = 0; m < 4; ++m)
#pragma unroll
    for (int n = 0; n < 2; ++n)
#pragma unroll
      for (int r = 0; r < 16; ++r) acc[m][n][r] = 0.f;

  const int NT = K >> 6;   // BK=64; all K are multiples of 64, NT >= 3

  // prologue: tile 0 (4 HT) -> buf0; tile 1 first 3 HTs -> buf1
  STAGE_A(0, 0, 0);
  STAGE_A(1, 0, 0);
  STAGE_B(0, 0, 0);
  STAGE_B(1, 0, 0);
  STAGE_B(0, 1, 65536);
  STAGE_A(0, 1, 65536);
  STAGE_B(1, 1, 65536);
  asm volatile("s_waitcnt vmcnt(6)" ::: "memory");   // tile 0 landed; 3 HT in flight
  __builtin_amdgcn_sched_barrier(0);
  __builtin_amdgcn_s_barrier();

#define PHASE_TAIL()                                                         \
    __builtin_amdgcn_sched_barrier(0);                                       \
    __builtin_amdgcn_s_barrier();                                            \
    asm volatile("s_waitcnt lgkmcnt(0)" ::: "memory");                       \
    __builtin_amdgcn_sched_barrier(0);

#define MFMA8(MB)                                                            \
    __builtin_amdgcn_s_setprio(1);                                           \
    _Pragma("unroll") for (int kk = 0; kk < 2; ++kk)                         \
      _Pragma("unroll") for (int mm = 0; mm < 2; ++mm)                       \
        _Pragma("unroll") for (int nn = 0; nn < 2; ++nn)                     \
          acc[(MB) + mm][nn] = __builtin_amdgcn_mfma_f32_32x32x16_bf16(      \
              av[mm][kk], bv[nn][kk], acc[(MB) + mm][nn], 0, 0, 0);          \
    __builtin_amdgcn_s_setprio(0);                                           \
    __builtin_amdgcn_sched_barrier(0);                                       \
    __builtin_amdgcn_s_barrier();

#define TILE32(TT, S1, S234, DO_VM)                                          \
  {                                                                          \
    const int bufC = ((TT) & 1) * 65536;                                     \
    const int bufN = 65536 - bufC;                                           \
    bf16x8 av[2][2], bv[2][2];                                               \
    /* ---- phase 1: kk4 0-1, m0-1, read B kk4 0-1 ---- */                   \
    _Pragma("unroll") for (int mm = 0; mm < 2; ++mm)                         \
      _Pragma("unroll") for (int kk = 0; kk < 2; ++kk)                       \
        av[mm][kk] = *(const bf16x8*)(ldsb + bufC + aoffs[kk] + mm * 2048);  \
    _Pragma("unroll") for (int nn = 0; nn < 2; ++nn)                         \
      _Pragma("unroll") for (int kk = 0; kk < 2; ++kk)                       \
        bv[nn][kk] = *(const bf16x8*)(ldsb + bufC + boffs[kk] + nn * 2048);  \
    if (S1) { STAGE_A(1, (TT) + 1, bufN); }                                  \
    PHASE_TAIL()                                                             \
    MFMA8(0)                                                                 \
    /* ---- phase 2: kk4 0-1, m2-3 (B reused) ---- */                        \
    _Pragma("unroll") for (int mm = 0; mm < 2; ++mm)                         \
      _Pragma("unroll") for (int kk = 0; kk < 2; ++kk)                       \
        av[mm][kk] = *(const bf16x8*)(ldsb + bufC + aoffs[kk] + (mm + 2) * 2048); \
    if (S234) { STAGE_B(0, (TT) + 2, bufC); }                                \
    PHASE_TAIL()                                                             \
    MFMA8(2)                                                                 \
    /* ---- phase 3: kk4 2-3, m0-1, read B kk4 2-3 ---- */                   \
    _Pragma("unroll") for (int mm = 0; mm < 2; ++mm)                         \
      _Pragma("unroll") for (int kk = 0; kk < 2; ++kk)                       \
        av[mm][kk] = *(const bf16x8*)(ldsb + bufC + aoffs[kk + 2] + mm * 2048); \
    _Pragma("unroll") for (int nn = 0; nn < 2; ++nn)                         \
      _Pragma("unroll") for (int kk = 0; kk < 2; ++kk)                       \
        bv[nn][kk] = *(const bf16x8*)(ldsb + bufC + boffs[kk + 2] + nn * 2048); \
    if (S234) { STAGE_A(0, (TT) + 2, bufC); }                                \
    PHASE_TAIL()                                                             \
    MFMA8(0)                                                                 \
    /* ---- phase 4: kk4 2-3, m2-3 ---- */                                   \
    _Pragma("unroll") for (int mm = 0; mm < 2; ++mm)                         \
      _Pragma("unroll") for (int kk = 0; kk < 2; ++kk)                       \
        av[mm][kk] = *(const bf16x8*)(ldsb + bufC + aoffs[kk + 2] + (mm + 2) * 2048); \
    if (S234) { STAGE_B(1, (TT) + 2, bufC); }                                \
    __builtin_amdgcn_sched_barrier(0);                                       \
    __builtin_amdgcn_s_barrier();                                            \
    asm volatile("s_waitcnt lgkmcnt(0)" ::: "memory");                       \
    __builtin_amdgcn_sched_barrier(0);                                       \
    __builtin_amdgcn_s_setprio(1);                                           \
    _Pragma("unroll") for (int kk = 0; kk < 2; ++kk)                         \
      _Pragma("unroll") for (int mm = 0; mm < 2; ++mm)                       \
        _Pragma("unroll") for (int nn = 0; nn < 2; ++nn)                     \
          acc[mm + 2][nn] = __builtin_amdgcn_mfma_f32_32x32x16_bf16(         \
              av[mm][kk], bv[nn][kk], acc[mm + 2][nn], 0, 0, 0);             \
    __builtin_amdgcn_s_setprio(0);                                           \
    __builtin_amdgcn_sched_barrier(0);                                       \
    if (DO_VM == 1) asm volatile("s_waitcnt vmcnt(6)" ::: "memory");         \
    if (DO_VM == 2) asm volatile("s_waitcnt vmcnt(0)" ::: "memory");         \
    __builtin_amdgcn_sched_barrier(0);                                       \
    __builtin_amdgcn_s_barrier();                                            \
  }

  for (int T = 0; T < NT - 2; ++T) {
    TILE32(T, 1, 1, 1)
  }
  TILE32(NT - 2, 1, 0, 2)
  TILE32(NT - 1, 0, 0, 0)
#undef TILE32
#undef MFMA8
#undef PHASE_TAIL
#undef STAGE_A
#undef STAGE_B

  // ---- epilogue ---- 32x32 C/D: col = l31, row = (r&3)+8*(r>>2)+4*hi
  if (MODE == 0) {
    // bf16 + relu -> per-wave LDS bounce [128 rows][128 B] (2-way max = free)
#pragma unroll
    for (int n = 0; n < 2; ++n) {
      float bb = bias[n0 + wc * 64 + n * 32 + l31];
#pragma unroll
      for (int m = 0; m < 4; ++m)
#pragma unroll
        for (int r = 0; r < 16; ++r) {
          float v = fmaxf(acc[m][n][r] + bb, 0.f);
          int lrow = m * 32 + (r & 3) + 8 * (r >> 2) + 4 * hi;
          *(unsigned short*)(ldsb + w * 16384 + lrow * 128 + (n * 32 + l31) * 2) = f2bf(v);
        }
    }
    asm volatile("s_waitcnt lgkmcnt(0)" ::: "memory");   // own-wave region only
    __builtin_amdgcn_sched_barrier(0);
    unsigned short* Cb = Cout + (size_t)(m0 + wr * 128) * N + n0 + wc * 64;
#pragma unroll
    for (int i = 0; i < 16; ++i) {
      int lrow = i * 8 + (lane >> 3);
      bf16x8 val = *(const bf16x8*)(ldsb + w * 16384 + lrow * 128 + (lane & 7) * 16);
      *(bf16x8*)(Cb + (size_t)lrow * N + (lane & 7) * 8) = val;
    }
  } else {
    // fused coupling: even col = S, odd = T (pair via shfl_xor 1);
    // xnew[row][2j+par] = xold[row][2j+par]*exp(S)+T; S partials -> part.
#pragma unroll
    for (int m = 0; m < 4; ++m) {
      float sr[16];
#pragma unroll
      for (int r = 0; r < 16; ++r) sr[r] = 0.f;
#pragma unroll
      for (int n = 0; n < 2; ++n) {
        int gcol = n0 + wc * 64 + n * 32 + l31;
        float bb = bias[gcol];
#pragma unroll
        for (int r = 0; r < 16; ++r) {
          float v = acc[m][n][r] + bb;
          float vp = __shfl_xor(v, 1);
          if (!(lane & 1)) {
            int grow = m0 + wr * 128 + m * 32 + (r & 3) + 8 * (r >> 2) + 4 * hi;
            size_t idx = (size_t)grow * N + gcol + par;
            xnew[idx] = xold[idx] * expf(v) + vp;
            sr[r] += v;
          }
        }
      }
#pragma unroll
      for (int r = 0; r < 16; ++r) {
        float s = sr[r];
        s += __shfl_xor(s, 2);
        s += __shfl_xor(s, 4);
        s += __shfl_xor(s, 8);
        s += __shfl_xor(s, 16);
        if (l31 == 0) {
          int grow = m0 + wr * 128 + m * 32 + (r & 3) + 8 * (r >> 2) + 4 * hi;
          part[(size_t)grow * 32 + bx * 4 + wc] = s;
        }
      }
    }
  }
}

// logdet[row] (= or +=) sum of 32 column-group partials
__global__ void reduce_logdet(const float* __restrict__ P, float* __restrict__ logdet, int add) {
  int row = blockIdx.x * 256 + threadIdx.x;
  float s = 0.f;
#pragma unroll
  for (int g = 0; g < 32; ++g) s += P[(size_t)row * 32 + g];
  logdet[row] = add ? (logdet[row] + s) : s;
}

extern "C" void kernel_launch(void* const* d_in, const int* in_sizes, int n_in,
                              void* d_out, int out_size, void* d_ws, size_t ws_size,
                              hipStream_t stream) {
  const float* z    = (const float*)d_in[0];
  const float* cond = (const float*)d_in[1];
  const float* W1   = (const float*)d_in[4];
  const float* b1   = (const float*)d_in[5];
  const float* W2   = (const float*)d_in[6];
  const float* b2   = (const float*)d_in[7];
  const float* W3   = (const float*)d_in[8];
  const float* b3   = (const float*)d_in[9];

  float* xout   = (float*)d_out;                 // [B, D]
  float* logdet = xout + (size_t)B_ * D_;        // [B]

  // workspace (160 MiB): Wt 32 MiB | H1 64 MiB (h1 / logdet partials) |
  //                      H2 64 MiB (A0 input acts / h2)
  char* ws = (char*)d_ws;
  unsigned short* Wt = (unsigned short*)ws;
  unsigned short* H1 = (unsigned short*)(ws + 33554432);
  unsigned short* H2 = (unsigned short*)(ws + 33554432 + 67108864);
  float* Pp = (float*)H1;          // [B][32] S-partials (H1 free during GEMM3)
  unsigned short* A0 = H2;

  for (int blk = 0; blk < 2; ++blk) {
    const float* W1b = W1 + (size_t)blk * KIN_ * H_;
    const float* W2b = W2 + (size_t)blk * H_ * H_;
    const float* W3b = W3 + (size_t)blk * H_ * D_;
    const float* b1b = b1 + (size_t)blk * H_;
    const float* b2b = b2 + (size_t)blk * H_;
    const float* b3b = b3 + (size_t)blk * D_;
    // identity channels: parity 1-blk (blk0: odd, blk1: even);
    // transformed channels: parity blk (blk0: even, blk1: odd).
    const float* xsrc = blk ? xout : z;

    // GEMM1: [B,1088] x [1088,4096]
    convT<<<dim3(H_ / 32, KIN_ / 32), 256, 0, stream>>>(W1b, Wt, KIN_, H_);
    build_act<<<dim3(5, B_), 256, 0, stream>>>(xsrc, cond, 1 - blk, A0);
    gemm8p<0><<<dim3((H_ / 256) * (B_ / 256)), 512, 0, stream>>>(
        A0, Wt, b1b, H1, nullptr, nullptr, nullptr, 0, B_, H_, KIN_);

    // GEMM2: [B,4096] x [4096,4096]
    convT<<<dim3(H_ / 32, H_ / 32), 256, 0, stream>>>(W2b, Wt, H_, H_);
    gemm8p<0><<<dim3((H_ / 256) * (B_ / 256)), 512, 0, stream>>>(
        H1, Wt, b2b, H2, nullptr, nullptr, nullptr, 0, B_, H_, H_);

    // GEMM3: [B,4096] x [4096,2048] with fused coupling epilogue
    convT<<<dim3(D_ / 32, H_ / 32), 256, 0, stream>>>(W3b, Wt, H_, D_);
    gemm8p<1><<<dim3((D_ / 256) * (B_ / 256)), 512, 0, stream>>>(
        H2, Wt, b3b, nullptr, z, xout, Pp, blk, B_, D_, H_);

    reduce_logdet<<<dim3(B_ / 256), 256, 0, stream>>>(Pp, logdet, blk);
  }
}